// Round 3
// 383.981 us; speedup vs baseline: 1.2028x; 1.2028x over previous
//
#include <hip/hip_runtime.h>
#include <math.h>

// Problem constants (fixed by reference setup_inputs):
//   stimuli: (16,16,304,608) fp32, eye: (16,16,6) fp32, out: (16,16,304,608) fp32
#define IMG_H 304
#define IMG_W 608
#define IMG_HW (IMG_H * IMG_W)   // 184832
#define TPB 128                  // 2 waves per block, 1 16x16 tile per wave

#define TILE 16
#define TILES_X (IMG_W / TILE)      // 38
#define TILES_Y (IMG_H / TILE)      // 19
#define NTILES (TILES_X * TILES_Y)  // 722 = 361 blocks * 2 waves
#define TILES_PER_BLOCK 2

__global__ __launch_bounds__(TPB) void grid_sample_kernel(
    const float* __restrict__ stimuli,
    const float* __restrict__ eye,
    float* __restrict__ out)
{
    // Keep all implicit mul/add UNFUSED (hipcc device default is
    // -ffp-contract=fast-honor-pragmas). The only FMAs are the explicit
    // fmaf() calls modeling the einsum/dot accumulation chain.
    #pragma clang fp contract(off)

    const int bf = blockIdx.y;
    const float* __restrict__ img = stimuli + (size_t)bf * IMG_HW;
    float* __restrict__ o = out + (size_t)bf * IMG_HW;

    // Affine params (f32). Wave-uniform loads -> scalar broadcast.
    const float a0 = eye[bf * 6 + 0];
    const float a1 = eye[bf * 6 + 1];
    const float a2 = eye[bf * 6 + 2];
    const float a3 = eye[bf * 6 + 3];
    const float a4 = eye[bf * 6 + 4];
    const float a5 = eye[bf * 6 + 5];

    // 2D tile mapping: one 16x16 output tile per wave. Bounds the gather
    // footprint of every 64-lane memory instruction to the affine image of
    // a 16x16 patch (~16-20 cache lines) instead of the ~40-64 lines a
    // 512-px row strip spans. Per-pixel arithmetic below is IDENTICAL to
    // the verified linear-mapping kernel (output is bit-identical).
    const int wave = threadIdx.x >> 6;
    const int lane = threadIdx.x & 63;
    const int t = blockIdx.x * TILES_PER_BLOCK + wave;   // 0..721
    const int tile_r = t / TILES_X;
    const int tile_c = t - tile_r * TILES_X;
    const int row = tile_r * TILE + (lane >> 2);          // 16 rows per wave
    const int col = tile_c * TILE + ((lane & 3) << 2);    // 4 threads x 4 px

    // jnp.linspace(-1, 1, N, dtype=f32) semantics (modern JAX):
    //   t = iota(N-1)/(N-1)  (f32 division)
    //   out = fl(t - fl(1-t)); endpoint appended exactly as 1.0f.
    float yg;
    if (row == IMG_H - 1) {
        yg = 1.0f;
    } else {
        const float ty = (float)row / 303.0f;         // correctly-rounded f32 div
        yg = ty - (1.0f - ty);                        // unfused (contract off)
    }

    float res[4];
#pragma unroll
    for (int i = 0; i < 4; ++i) {
        const int j = col + i;
        float xg;
        if (j == IMG_W - 1) {
            xg = 1.0f;
        } else {
            const float tx = (float)j / 607.0f;
            xg = tx - (1.0f - tx);
        }

        // einsum 'bfij,jp->bfip' as an f32 FMA accumulation chain over j:
        const float xs = fmaf(a1, yg, a0 * xg) + a2;
        const float ys = fmaf(a4, yg, a3 * xg) + a5;

        // (x + 1.0) * W / 2.0 — separate f32 ops (unfused; div by 2 exact)
        const float x = ((xs + 1.0f) * (float)IMG_W) / 2.0f;
        const float y = ((ys + 1.0f) * (float)IMG_H) / 2.0f;

        const float fx0 = floorf(x);
        const float fy0 = floorf(y);
        int x0 = (int)fx0;
        int y0 = (int)fy0;
        int x1 = x0 + 1;
        int y1 = y0 + 1;
        x0 = min(max(x0, 0), IMG_W - 1);
        x1 = min(max(x1, 0), IMG_W - 1);
        y0 = min(max(y0, 0), IMG_H - 1);
        y1 = min(max(y1, 0), IMG_H - 1);

        const float x0f = (float)x0, x1f = (float)x1;
        const float y0f = (float)y0, y1f = (float)y1;

        const float Ia = img[y0 * IMG_W + x0];
        const float Ib = img[y1 * IMG_W + x0];
        const float Ic = img[y0 * IMG_W + x1];
        const float Id = img[y1 * IMG_W + x1];

        // elementwise f32 weight arithmetic, unfused
        const float wxa = x1f - x;
        const float wxb = x - x0f;
        const float wya = y1f - y;
        const float wyb = y - y0f;

        const float wa = wxa * wya;
        const float wb = wxa * wyb;
        const float wc = wxb * wya;
        const float wd = wxb * wyb;

        // ((wa*Ia + wb*Ib) + wc*Ic) + wd*Id, left-assoc, unfused
        const float s0 = (wa * Ia) + (wb * Ib);
        const float s1 = s0 + (wc * Ic);
        res[i] = s1 + (wd * Id);
    }

    float4 v = make_float4(res[0], res[1], res[2], res[3]);
    *reinterpret_cast<float4*>(o + (size_t)row * IMG_W + col) = v;
}

extern "C" void kernel_launch(void* const* d_in, const int* in_sizes, int n_in,
                              void* d_out, int out_size, void* d_ws, size_t ws_size,
                              hipStream_t stream) {
    const float* stimuli = (const float*)d_in[0];
    const float* eye     = (const float*)d_in[1];
    float* out           = (float*)d_out;

    const int n_imgs = in_sizes[1] / 6;              // 256
    const int blocks_x = NTILES / TILES_PER_BLOCK;   // 361
    dim3 grid(blocks_x, n_imgs);
    grid_sample_kernel<<<grid, TPB, 0, stream>>>(stimuli, eye, out);
}

// Round 4
// 357.514 us; speedup vs baseline: 1.2918x; 1.0740x over previous
//
#include <hip/hip_runtime.h>
#include <math.h>

// Problem constants (fixed by reference setup_inputs):
//   stimuli: (16,16,304,608) fp32, eye: (16,16,6) fp32, out: (16,16,304,608) fp32
#define IMG_H 304
#define IMG_W 608
#define IMG_HW (IMG_H * IMG_W)   // 184832
#define TPB 128                  // 2 waves per block, 1 16x16 tile per wave

#define TILE 16
#define TILES_X (IMG_W / TILE)   // 38
#define TILES_Y (IMG_H / TILE)   // 19
#define NTILES (TILES_X * TILES_Y)  // 722 = 361 blocks * 2 waves
#define TILES_PER_BLOCK 2

// 8-byte vector load with only 4-byte alignment guarantee (x0 is arbitrary).
// Compiler emits global_load_dwordx2 under unaligned-access-mode, or two
// dword loads sharing one base address otherwise — correct either way.
typedef float f2u __attribute__((ext_vector_type(2), aligned(4)));
typedef float f4v __attribute__((ext_vector_type(4)));

__global__ __launch_bounds__(TPB) void grid_sample_kernel(
    const float* __restrict__ stimuli,
    const float* __restrict__ eye,
    float* __restrict__ out)
{
    // Keep all implicit mul/add UNFUSED (hipcc device default is
    // -ffp-contract=fast-honor-pragmas). The only FMAs are the explicit
    // fmaf() calls modeling the einsum/dot accumulation chain.
    #pragma clang fp contract(off)

    const int bf = blockIdx.y;
    const float* __restrict__ img = stimuli + (size_t)bf * IMG_HW;
    float* __restrict__ o = out + (size_t)bf * IMG_HW;

    // Affine params (f32). Wave-uniform loads -> scalar broadcast.
    const float a0 = eye[bf * 6 + 0];
    const float a1 = eye[bf * 6 + 1];
    const float a2 = eye[bf * 6 + 2];
    const float a3 = eye[bf * 6 + 3];
    const float a4 = eye[bf * 6 + 4];
    const float a5 = eye[bf * 6 + 5];

    // 2D tile mapping: one 16x16 output tile per wave (verified round 3:
    // 239 -> 156 us/dispatch). Bounds every 64-lane gather's footprint to
    // the affine image of a 16x16 patch.
    const int wave = threadIdx.x >> 6;
    const int lane = threadIdx.x & 63;
    const int t = blockIdx.x * TILES_PER_BLOCK + wave;   // 0..721
    const int tile_r = t / TILES_X;
    const int tile_c = t - tile_r * TILES_X;
    const int row = tile_r * TILE + (lane >> 2);          // 16 rows per wave
    const int col = tile_c * TILE + ((lane & 3) << 2);    // 4 threads x 4 px

    // jnp.linspace(-1, 1, N, dtype=f32) semantics (modern JAX):
    //   t = iota(N-1)/(N-1)  (f32 division)
    //   out = fl(t - fl(1-t)); endpoint appended exactly as 1.0f.
    float yg;
    if (row == IMG_H - 1) {
        yg = 1.0f;
    } else {
        const float ty = (float)row / 303.0f;         // correctly-rounded f32 div
        yg = ty - (1.0f - ty);                        // unfused (contract off)
    }

    float res[4];
#pragma unroll
    for (int i = 0; i < 4; ++i) {
        const int j = col + i;
        float xg;
        if (j == IMG_W - 1) {
            xg = 1.0f;
        } else {
            const float tx = (float)j / 607.0f;
            xg = tx - (1.0f - tx);
        }

        // einsum 'bfij,jp->bfip' as an f32 FMA accumulation chain over j:
        const float xs = fmaf(a1, yg, a0 * xg) + a2;
        const float ys = fmaf(a4, yg, a3 * xg) + a5;

        // (x + 1.0) * W / 2.0 — separate f32 ops (unfused; div by 2 exact)
        const float x = ((xs + 1.0f) * (float)IMG_W) / 2.0f;
        const float y = ((ys + 1.0f) * (float)IMG_H) / 2.0f;

        const float fx0 = floorf(x);
        const float fy0 = floorf(y);
        const int x0 = (int)fx0;
        const int y0 = (int)fy0;

        const int x0c = min(max(x0, 0), IMG_W - 1);
        const int x1c = min(max(x0 + 1, 0), IMG_W - 1);
        const int y0c = min(max(y0, 0), IMG_H - 1);
        const int y1c = min(max(y0 + 1, 0), IMG_H - 1);

        // Paired corner loads. xp in [0, W-2]; {P0,P1} = img[row, xp..xp+1].
        // Clamp-case select (exact, all cases):
        //   x0 in [0,W-2]: Ia=P0, Ic=P1
        //   x0 <  0      : x0c=x1c=max(x0+1,0)=0 -> both img[row,0]=P0
        //   x0 == W-1    : x0c=x1c=W-1, xp=W-2   -> both P1
        //   x0 >= W      : x0c=x1c=W-1           -> both P1
        const int xp = min(x0c, IMG_W - 2);
        const f2u ra = *reinterpret_cast<const f2u*>(img + y0c * IMG_W + xp);
        const f2u rb = *reinterpret_cast<const f2u*>(img + y1c * IMG_W + xp);

        const bool hi = (x0 >= IMG_W - 1);   // Ia/Ib come from the right slot
        const bool lo = (x0 < 0);            // Ic/Id come from the left slot
        const float Ia = hi ? ra.y : ra.x;
        const float Ic = lo ? ra.x : ra.y;
        const float Ib = hi ? rb.y : rb.x;
        const float Id = lo ? rb.x : rb.y;

        const float x0f = (float)x0c, x1f = (float)x1c;
        const float y0f = (float)y0c, y1f = (float)y1c;

        // elementwise f32 weight arithmetic, unfused
        const float wxa = x1f - x;
        const float wxb = x - x0f;
        const float wya = y1f - y;
        const float wyb = y - y0f;

        const float wa = wxa * wya;
        const float wb = wxa * wyb;
        const float wc = wxb * wya;
        const float wd = wxb * wyb;

        // ((wa*Ia + wb*Ib) + wc*Ic) + wd*Id, left-assoc, unfused
        const float s0 = (wa * Ia) + (wb * Ib);
        const float s1 = s0 + (wc * Ic);
        res[i] = s1 + (wd * Id);
    }

    // Output stream (185 MB/dispatch) is write-once: non-temporal store
    // keeps L2 capacity for the gather working set.
    f4v v = { res[0], res[1], res[2], res[3] };
    __builtin_nontemporal_store(
        v, reinterpret_cast<f4v*>(o + (size_t)row * IMG_W + col));
}

extern "C" void kernel_launch(void* const* d_in, const int* in_sizes, int n_in,
                              void* d_out, int out_size, void* d_ws, size_t ws_size,
                              hipStream_t stream) {
    const float* stimuli = (const float*)d_in[0];
    const float* eye     = (const float*)d_in[1];
    float* out           = (float*)d_out;

    const int n_imgs = in_sizes[1] / 6;              // 256
    const int blocks_x = NTILES / TILES_PER_BLOCK;   // 361
    dim3 grid(blocks_x, n_imgs);
    grid_sample_kernel<<<grid, TPB, 0, stream>>>(stimuli, eye, out);
}